// Round 11
// baseline (174.552 us; speedup 1.0000x reference)
//
#include <hip/hip_runtime.h>
#include <hip/hip_bf16.h>

// SNN "SynapticChain": B=4, T=24, N=4096, F=32, L=3 (+1 final synaptic layer).
// R11: TWO-KERNEL SPLIT. The MLP (63% of VALU work) has no feedback into the
// recurrence -> run it as a separate, fully parallel, high-occupancy kernel.
//   K1 snn_chain: R10's 2-row/lane recurrent chain (LUT+ballot), writes
//      `transformed` into d_out. 64KB LUT, (512,2).
//   K2 snn_mlp: R10's DPP-systolic MLP (bf16-packed weights, dir-probe,
//      xor16 swizzle) IN-PLACE on d_out. No LDS, grid-stride 2048 blocks,
//      (256,4) -> 128-VGPR cap under both launch_bounds semantics.
// In-place safety: each lane reads only its own (row,l) element; all
// cross-feature traffic is DPP/swizzle in-register. Math identical to R10.

namespace {
constexpr int kB = 4;
constexpr int kT = 24;
constexpr int kN = 4096;
constexpr int kF = 32;
constexpr int kNF = kN * kF;
constexpr int kRowsTot = kB * kT * kN;   // 393216 independent MLP rows

template<int S>
__device__ __forceinline__ float ror16(float x) {
    static_assert(S >= 1 && S <= 15, "row_ror range");
    return __int_as_float(__builtin_amdgcn_update_dpp(
        0, __float_as_int(x), 0x120 | S, 0xF, 0xF, true));
}

__device__ __forceinline__ float swz_x16(float x) {
    // ds_swizzle bitmode: and=0x1F, or=0, xor=0x10 -> lane ^ 16
    return __int_as_float(__builtin_amdgcn_ds_swizzle(__float_as_int(x), 0x401F));
}

__device__ __forceinline__ unsigned pack_bf16(float lo, float hi) {
    unsigned a = (unsigned)__bfloat16_as_ushort(__float2bfloat16(lo));
    unsigned b = (unsigned)__bfloat16_as_ushort(__float2bfloat16(hi));
    return a | (b << 16);
}

template<int S>
__device__ __forceinline__ float upk(const unsigned* wp) {
    const unsigned r = wp[S >> 1];
    if constexpr (S & 1) return __int_as_float(r & 0xffff0000u);
    else                 return __int_as_float(r << 16);
}

// MLP1 for two rows: weights unpacked ONCE, FMA'd into both rows' accs.
template<int S>
__device__ __forceinline__ void mlp1_steps2(float tvA, float tvB,
        const unsigned* w_oa, const unsigned* w_ob,
        const unsigned* w_xa, const unsigned* w_xb,
        float& oaA, float& obA, float& xaA, float& xbA,
        float& oaB, float& obB, float& xaB, float& xbB) {
    if constexpr (S <= 15) {
        float vA, vB;
        if constexpr (S == 0) { vA = tvA; vB = tvB; }
        else { vA = ror16<S>(tvA); vB = ror16<S>(tvB); }
        const float w0 = upk<S>(w_oa);
        const float w1 = upk<S>(w_ob);
        const float w2 = upk<S>(w_xa);
        const float w3 = upk<S>(w_xb);
        oaA = fmaf(vA, w0, oaA);  oaB = fmaf(vB, w0, oaB);
        obA = fmaf(vA, w1, obA);  obB = fmaf(vB, w1, obB);
        xaA = fmaf(vA, w2, xaA);  xaB = fmaf(vB, w2, xaB);
        xbA = fmaf(vA, w3, xbA);  xbB = fmaf(vB, w3, xbB);
        mlp1_steps2<S + 1>(tvA, tvB, w_oa, w_ob, w_xa, w_xb,
                           oaA, obA, xaA, xbA, oaB, obB, xaB, xbB);
    }
}

// MLP2 for two rows: 4 shared unpacks, 8 FMAs per step.
template<int S>
__device__ __forceinline__ void mlp2_steps2(
        float u0A, float u1A, float u0B, float u1B,
        const unsigned* w_o0, const unsigned* w_o1,
        const unsigned* w_x0, const unsigned* w_x1,
        float& ooA, float& xxA, float& ooB, float& xxB) {
    if constexpr (S <= 15) {
        float v0A, v1A, v0B, v1B;
        if constexpr (S == 0) { v0A = u0A; v1A = u1A; v0B = u0B; v1B = u1B; }
        else {
            v0A = ror16<S>(u0A); v1A = ror16<S>(u1A);
            v0B = ror16<S>(u0B); v1B = ror16<S>(u1B);
        }
        const float w0 = upk<S>(w_o0);
        const float w1 = upk<S>(w_o1);
        const float w2 = upk<S>(w_x0);
        const float w3 = upk<S>(w_x1);
        ooA = fmaf(v0A, w0, ooA);  ooB = fmaf(v0B, w0, ooB);
        ooA = fmaf(v1A, w1, ooA);  ooB = fmaf(v1B, w1, ooB);
        xxA = fmaf(v0A, w2, xxA);  xxB = fmaf(v0B, w2, xxB);
        xxA = fmaf(v1A, w3, xxA);  xxB = fmaf(v1B, w3, xxB);
        mlp2_steps2<S + 1>(u0A, u1A, u0B, u1B, w_o0, w_o1, w_x0, w_x1,
                           ooA, xxA, ooB, xxB);
    }
}

// ---------------- Kernel 1: recurrent chain -> transformed ----------------
__global__ __launch_bounds__(512, 2)
void snn_chain(const float* __restrict__ x,
               const float* __restrict__ alphas,
               const float* __restrict__ betas,
               const float* __restrict__ thrs,
               const float* __restrict__ chain_W,
               const float* __restrict__ chain_b,
               const float* __restrict__ lin_W,
               const float* __restrict__ lin_b,
               float* __restrict__ out)
{
    const int tid  = threadIdx.x;
    const int lane = tid & 63;
    const int half = lane >> 5;
    const int l    = lane & 31;
    const int wid  = tid >> 6;              // 0..7
    const int rowA = blockIdx.x * 32 + wid * 4 + half;
    const int rowB = rowA + 2;
    const int bA   = rowA >> 12;
    const int nA   = rowA & (kN - 1);
    const int bB   = rowB >> 12;
    const int nB   = rowB & (kN - 1);

    __shared__ float lut[4][8][16][32];     // 64 KB

#pragma unroll
    for (int c = 0; c < 2; ++c) {
        const int idx = tid + c * 512;
        const int mat = idx >> 8;
        const int g   = (idx >> 5) & 7;
        const int jj  = idx & 31;
        const float* wsrc = (mat < 3) ? (chain_W + ((mat * kF + jj) * kF + g * 4))
                                      : (lin_W + (jj * kF + g * 4));
        const float4 w = *reinterpret_cast<const float4*>(wsrc);
        const float bias = (g == 0) ? ((mat < 3) ? chain_b[mat * kF + jj] : lin_b[jj])
                                    : 0.0f;
        float s[16];
        s[0]  = 0.0f;
        s[1]  = w.x;         s[2]  = w.y;         s[3]  = w.x + w.y;
        s[4]  = w.z;         s[5]  = w.x + w.z;   s[6]  = w.y + w.z;
        s[7]  = s[3] + w.z;  s[8]  = w.w;         s[9]  = w.x + w.w;
        s[10] = w.y + w.w;   s[11] = s[3] + w.w;  s[12] = w.z + w.w;
        s[13] = s[5] + w.w;  s[14] = s[6] + w.w;  s[15] = s[7] + w.w;
#pragma unroll
        for (int nb = 0; nb < 16; ++nb) lut[mat][g][nb][jj] = s[nb] + bias;
    }
    __syncthreads();

    float al[4], be[4], th[4];
#pragma unroll
    for (int i = 0; i < 4; ++i) {
        al[i] = fminf(fmaxf(alphas[i], 0.0f), 1.0f);
        be[i] = fminf(fmaxf(betas[i],  0.0f), 1.0f);
        th[i] = thrs[i];
    }

    float synA[4] = {0.f, 0.f, 0.f, 0.f};
    float memA[4] = {0.f, 0.f, 0.f, 0.f};
    float synB[4] = {0.f, 0.f, 0.f, 0.f};
    float memB[4] = {0.f, 0.f, 0.f, 0.f};

    const float* xpA = x   + (bA * kT * kN + nA) * kF + l;
    float*       opA = out + (bA * kT * kN + nA) * kF + l;
    const float* xpB = x   + (bB * kT * kN + nB) * kF + l;
    float*       opB = out + (bB * kT * kN + nB) * kF + l;

    float xvA = xpA[0];
    float xvB = xpB[0];

    for (int t = 0; t < kT; ++t) {
        float xnA = 0.0f, xnB = 0.0f;
        if (t + 1 < kT) { xnA = xpA[(t + 1) * kNF]; xnB = xpB[(t + 1) * kNF]; }

        float hA = xvA, hB = xvB;
        float trA = 0.0f, trB = 0.0f;

#pragma unroll
        for (int i = 0; i < 4; ++i) {
            const float rstA = ((memA[i] - th[i]) > 0.0f) ? 1.0f : 0.0f;
            const float rstB = ((memB[i] - th[i]) > 0.0f) ? 1.0f : 0.0f;
            synA[i] = al[i] * synA[i] + hA;
            synB[i] = al[i] * synB[i] + hB;
            memA[i] = be[i] * memA[i] + synA[i] - rstA * th[i];
            memB[i] = be[i] * memB[i] + synB[i] - rstB * th[i];
            const bool spA = (memA[i] - th[i]) > 0.0f;
            const bool spB = (memB[i] - th[i]) > 0.0f;

            const unsigned long long a64 = __ballot(spA);
            const unsigned long long b64 = __ballot(spB);
            const unsigned mA = half ? (unsigned)(a64 >> 32) : (unsigned)a64;
            const unsigned mB = half ? (unsigned)(b64 >> 32) : (unsigned)b64;

            float vA[8], vB[8];
#pragma unroll
            for (int g = 0; g < 8; ++g) {
                vA[g] = lut[i][g][(mA >> (4 * g)) & 15u][l];
                vB[g] = lut[i][g][(mB >> (4 * g)) & 15u][l];
            }
            const float accA = ((vA[0] + vA[1]) + (vA[2] + vA[3]))
                             + ((vA[4] + vA[5]) + (vA[6] + vA[7]));
            const float accB = ((vB[0] + vB[1]) + (vB[2] + vB[3]))
                             + ((vB[4] + vB[5]) + (vB[6] + vB[7]));
            if (i < 3) { hA = accA; hB = accB; }
            else       { trA = accA; trB = accB; }
        }

        opA[t * kNF] = trA;
        opB[t * kNF] = trB;

        xvA = xnA;
        xvB = xnB;
    }
}

// ---------------- Kernel 2: feed-forward MLP, in-place on out -------------
__global__ __launch_bounds__(256, 4)
void snn_mlp(const float* __restrict__ W1,
             const float* __restrict__ b1,
             const float* __restrict__ prelu_a,
             const float* __restrict__ W2,
             const float* __restrict__ b2,
             float* out)
{
    const int tid  = threadIdx.x;
    const int lane = tid & 63;
    const int half = lane >> 5;
    const int l    = lane & 31;
    const int l16  = lane & 15;
    const int gbase= l & 16;
    const int gwave= (blockIdx.x * 256 + tid) >> 6;   // 0..8191

    const float pa = prelu_a[0];

    // DPP row_ror direction probe
    const int pr = __builtin_amdgcn_update_dpp(0, lane, 0x121, 0xF, 0xF, true);
    const int d  = (__builtin_amdgcn_readfirstlane(pr) == 1) ? 1 : 15;

    const int lx = l ^ 16;
    unsigned u1_oa[8], u1_ob[8], u1_xa[8], u1_xb[8];
    unsigned u2_o0[8], u2_o1[8], u2_x0[8], u2_x1[8];
#pragma unroll
    for (int q = 0; q < 8; ++q) {
        const int s0 = 2 * q, s1 = 2 * q + 1;
        const int i0 = ((l16 + d * s0) & 15) | gbase;
        const int i1 = ((l16 + d * s1) & 15) | gbase;
        u1_oa[q] = pack_bf16(W1[l         * kF + i0], W1[l         * kF + i1]);
        u1_ob[q] = pack_bf16(W1[(l + 32)  * kF + i0], W1[(l + 32)  * kF + i1]);
        u1_xa[q] = pack_bf16(W1[lx        * kF + i0], W1[lx        * kF + i1]);
        u1_xb[q] = pack_bf16(W1[(lx + 32) * kF + i0], W1[(lx + 32) * kF + i1]);
        u2_o0[q] = pack_bf16(W2[l  * 64 + i0],      W2[l  * 64 + i1]);
        u2_o1[q] = pack_bf16(W2[l  * 64 + i0 + 32], W2[l  * 64 + i1 + 32]);
        u2_x0[q] = pack_bf16(W2[lx * 64 + i0],      W2[lx * 64 + i1]);
        u2_x1[q] = pack_bf16(W2[lx * 64 + i0 + 32], W2[lx * 64 + i1 + 32]);
    }
    const float b1a = b1[l];
    const float b1b = b1[l + 32];
    const float ob  = b2[l];

    // grid-stride over row groups: wave handles rows {base, base+1, base+2, base+3}
    // (A = base+half, B = base+half+2); 8192 waves, 12 passes, exact cover.
    for (int base = gwave * 4; base < kRowsTot; base += 8192 * 4) {
        const int rA = base + half;
        const int rB = rA + 2;
        float* pA = out + rA * kF + l;
        float* pB = out + rB * kF + l;
        const float trA = *pA;
        const float trB = *pB;

        float oaA = b1a, obA = b1b, xaA = 0.0f, xbA = 0.0f;
        float oaB = b1a, obB = b1b, xaB = 0.0f, xbB = 0.0f;
        mlp1_steps2<0>(trA, trB, u1_oa, u1_ob, u1_xa, u1_xb,
                       oaA, obA, xaA, xbA, oaB, obB, xaB, xbB);
        const float h1aA = oaA + swz_x16(xaA);
        const float h1bA = obA + swz_x16(xbA);
        const float h1aB = oaB + swz_x16(xaB);
        const float h1bB = obB + swz_x16(xbB);
        const float g1A = (h1aA > 0.0f) ? h1aA : pa * h1aA;
        const float g2A = (h1bA > 0.0f) ? h1bA : pa * h1bA;
        const float g1B = (h1aB > 0.0f) ? h1aB : pa * h1aB;
        const float g2B = (h1bB > 0.0f) ? h1bB : pa * h1bB;

        float ooA = ob, xxA = 0.0f;
        float ooB = ob, xxB = 0.0f;
        mlp2_steps2<0>(g1A, g2A, g1B, g2B, u2_o0, u2_o1, u2_x0, u2_x1,
                       ooA, xxA, ooB, xxB);
        *pA = ooA + swz_x16(xxA);
        *pB = ooB + swz_x16(xxB);
    }
}
} // namespace

extern "C" void kernel_launch(void* const* d_in, const int* in_sizes, int n_in,
                              void* d_out, int out_size, void* d_ws, size_t ws_size,
                              hipStream_t stream) {
    const float* x        = (const float*)d_in[0];
    const float* alphas   = (const float*)d_in[1];
    const float* betas    = (const float*)d_in[2];
    const float* thrs     = (const float*)d_in[3];
    const float* chain_W  = (const float*)d_in[4];
    const float* chain_b  = (const float*)d_in[5];
    const float* lin_W    = (const float*)d_in[6];
    const float* lin_b    = (const float*)d_in[7];
    const float* W1       = (const float*)d_in[8];
    const float* b1       = (const float*)d_in[9];
    const float* prelu_a  = (const float*)d_in[10];
    const float* W2       = (const float*)d_in[11];
    const float* b2       = (const float*)d_in[12];
    float* out            = (float*)d_out;

    // K1: 16384 (b,n) rows / (8 waves * 4 rows) = 512 blocks
    hipLaunchKernelGGL(snn_chain, dim3(512), dim3(512), 0, stream,
                       x, alphas, betas, thrs, chain_W, chain_b, lin_W, lin_b, out);
    // K2: 393216 rows, grid-stride, 2048 blocks * 4 waves * 4 rows * 12 passes
    hipLaunchKernelGGL(snn_mlp, dim3(2048), dim3(256), 0, stream,
                       W1, b1, prelu_a, W2, b2, out);
}

// Round 12
// 160.541 us; speedup vs baseline: 1.0873x; 1.0873x over previous
//
#include <hip/hip_runtime.h>
#include <hip/hip_bf16.h>

// SNN "SynapticChain": B=4, T=24, N=4096, F=32, L=3 (+1 final synaptic layer).
// R12: two-kernel split (R11) with snn_mlp moved into the ONLY empirically
// proven non-64-VGPR envelope: 512 threads + __launch_bounds__(512,2)
// (R5/R6/R9/R10: 120/88/88/112 VGPR; every arg2>=4 or 1024-thread config
// pins 64 and spills). Kernel bodies identical to R11.
//   K1 snn_chain: recurrent chain (LUT+ballot), 2 rows/lane, ~33us measured.
//   K2 snn_mlp: DPP-systolic MLP in-place on d_out, bf16-packed weights,
//      2048 blocks x 8 waves, 6-pass grid-stride (exact cover).

namespace {
constexpr int kB = 4;
constexpr int kT = 24;
constexpr int kN = 4096;
constexpr int kF = 32;
constexpr int kNF = kN * kF;
constexpr int kRowsTot = kB * kT * kN;   // 393216 independent MLP rows

template<int S>
__device__ __forceinline__ float ror16(float x) {
    static_assert(S >= 1 && S <= 15, "row_ror range");
    return __int_as_float(__builtin_amdgcn_update_dpp(
        0, __float_as_int(x), 0x120 | S, 0xF, 0xF, true));
}

__device__ __forceinline__ float swz_x16(float x) {
    // ds_swizzle bitmode: and=0x1F, or=0, xor=0x10 -> lane ^ 16
    return __int_as_float(__builtin_amdgcn_ds_swizzle(__float_as_int(x), 0x401F));
}

__device__ __forceinline__ unsigned pack_bf16(float lo, float hi) {
    unsigned a = (unsigned)__bfloat16_as_ushort(__float2bfloat16(lo));
    unsigned b = (unsigned)__bfloat16_as_ushort(__float2bfloat16(hi));
    return a | (b << 16);
}

template<int S>
__device__ __forceinline__ float upk(const unsigned* wp) {
    const unsigned r = wp[S >> 1];
    if constexpr (S & 1) return __int_as_float(r & 0xffff0000u);
    else                 return __int_as_float(r << 16);
}

// MLP1 for two rows: weights unpacked ONCE, FMA'd into both rows' accs.
template<int S>
__device__ __forceinline__ void mlp1_steps2(float tvA, float tvB,
        const unsigned* w_oa, const unsigned* w_ob,
        const unsigned* w_xa, const unsigned* w_xb,
        float& oaA, float& obA, float& xaA, float& xbA,
        float& oaB, float& obB, float& xaB, float& xbB) {
    if constexpr (S <= 15) {
        float vA, vB;
        if constexpr (S == 0) { vA = tvA; vB = tvB; }
        else { vA = ror16<S>(tvA); vB = ror16<S>(tvB); }
        const float w0 = upk<S>(w_oa);
        const float w1 = upk<S>(w_ob);
        const float w2 = upk<S>(w_xa);
        const float w3 = upk<S>(w_xb);
        oaA = fmaf(vA, w0, oaA);  oaB = fmaf(vB, w0, oaB);
        obA = fmaf(vA, w1, obA);  obB = fmaf(vB, w1, obB);
        xaA = fmaf(vA, w2, xaA);  xaB = fmaf(vB, w2, xaB);
        xbA = fmaf(vA, w3, xbA);  xbB = fmaf(vB, w3, xbB);
        mlp1_steps2<S + 1>(tvA, tvB, w_oa, w_ob, w_xa, w_xb,
                           oaA, obA, xaA, xbA, oaB, obB, xaB, xbB);
    }
}

// MLP2 for two rows: 4 shared unpacks, 8 FMAs per step.
template<int S>
__device__ __forceinline__ void mlp2_steps2(
        float u0A, float u1A, float u0B, float u1B,
        const unsigned* w_o0, const unsigned* w_o1,
        const unsigned* w_x0, const unsigned* w_x1,
        float& ooA, float& xxA, float& ooB, float& xxB) {
    if constexpr (S <= 15) {
        float v0A, v1A, v0B, v1B;
        if constexpr (S == 0) { v0A = u0A; v1A = u1A; v0B = u0B; v1B = u1B; }
        else {
            v0A = ror16<S>(u0A); v1A = ror16<S>(u1A);
            v0B = ror16<S>(u0B); v1B = ror16<S>(u1B);
        }
        const float w0 = upk<S>(w_o0);
        const float w1 = upk<S>(w_o1);
        const float w2 = upk<S>(w_x0);
        const float w3 = upk<S>(w_x1);
        ooA = fmaf(v0A, w0, ooA);  ooB = fmaf(v0B, w0, ooB);
        ooA = fmaf(v1A, w1, ooA);  ooB = fmaf(v1B, w1, ooB);
        xxA = fmaf(v0A, w2, xxA);  xxB = fmaf(v0B, w2, xxB);
        xxA = fmaf(v1A, w3, xxA);  xxB = fmaf(v1B, w3, xxB);
        mlp2_steps2<S + 1>(u0A, u1A, u0B, u1B, w_o0, w_o1, w_x0, w_x1,
                           ooA, xxA, ooB, xxB);
    }
}

// ---------------- Kernel 1: recurrent chain -> transformed ----------------
__global__ __launch_bounds__(512, 2)
void snn_chain(const float* __restrict__ x,
               const float* __restrict__ alphas,
               const float* __restrict__ betas,
               const float* __restrict__ thrs,
               const float* __restrict__ chain_W,
               const float* __restrict__ chain_b,
               const float* __restrict__ lin_W,
               const float* __restrict__ lin_b,
               float* __restrict__ out)
{
    const int tid  = threadIdx.x;
    const int lane = tid & 63;
    const int half = lane >> 5;
    const int l    = lane & 31;
    const int wid  = tid >> 6;              // 0..7
    const int rowA = blockIdx.x * 32 + wid * 4 + half;
    const int rowB = rowA + 2;
    const int bA   = rowA >> 12;
    const int nA   = rowA & (kN - 1);
    const int bB   = rowB >> 12;
    const int nB   = rowB & (kN - 1);

    __shared__ float lut[4][8][16][32];     // 64 KB

#pragma unroll
    for (int c = 0; c < 2; ++c) {
        const int idx = tid + c * 512;
        const int mat = idx >> 8;
        const int g   = (idx >> 5) & 7;
        const int jj  = idx & 31;
        const float* wsrc = (mat < 3) ? (chain_W + ((mat * kF + jj) * kF + g * 4))
                                      : (lin_W + (jj * kF + g * 4));
        const float4 w = *reinterpret_cast<const float4*>(wsrc);
        const float bias = (g == 0) ? ((mat < 3) ? chain_b[mat * kF + jj] : lin_b[jj])
                                    : 0.0f;
        float s[16];
        s[0]  = 0.0f;
        s[1]  = w.x;         s[2]  = w.y;         s[3]  = w.x + w.y;
        s[4]  = w.z;         s[5]  = w.x + w.z;   s[6]  = w.y + w.z;
        s[7]  = s[3] + w.z;  s[8]  = w.w;         s[9]  = w.x + w.w;
        s[10] = w.y + w.w;   s[11] = s[3] + w.w;  s[12] = w.z + w.w;
        s[13] = s[5] + w.w;  s[14] = s[6] + w.w;  s[15] = s[7] + w.w;
#pragma unroll
        for (int nb = 0; nb < 16; ++nb) lut[mat][g][nb][jj] = s[nb] + bias;
    }
    __syncthreads();

    float al[4], be[4], th[4];
#pragma unroll
    for (int i = 0; i < 4; ++i) {
        al[i] = fminf(fmaxf(alphas[i], 0.0f), 1.0f);
        be[i] = fminf(fmaxf(betas[i],  0.0f), 1.0f);
        th[i] = thrs[i];
    }

    float synA[4] = {0.f, 0.f, 0.f, 0.f};
    float memA[4] = {0.f, 0.f, 0.f, 0.f};
    float synB[4] = {0.f, 0.f, 0.f, 0.f};
    float memB[4] = {0.f, 0.f, 0.f, 0.f};

    const float* xpA = x   + (bA * kT * kN + nA) * kF + l;
    float*       opA = out + (bA * kT * kN + nA) * kF + l;
    const float* xpB = x   + (bB * kT * kN + nB) * kF + l;
    float*       opB = out + (bB * kT * kN + nB) * kF + l;

    float xvA = xpA[0];
    float xvB = xpB[0];

    for (int t = 0; t < kT; ++t) {
        float xnA = 0.0f, xnB = 0.0f;
        if (t + 1 < kT) { xnA = xpA[(t + 1) * kNF]; xnB = xpB[(t + 1) * kNF]; }

        float hA = xvA, hB = xvB;
        float trA = 0.0f, trB = 0.0f;

#pragma unroll
        for (int i = 0; i < 4; ++i) {
            const float rstA = ((memA[i] - th[i]) > 0.0f) ? 1.0f : 0.0f;
            const float rstB = ((memB[i] - th[i]) > 0.0f) ? 1.0f : 0.0f;
            synA[i] = al[i] * synA[i] + hA;
            synB[i] = al[i] * synB[i] + hB;
            memA[i] = be[i] * memA[i] + synA[i] - rstA * th[i];
            memB[i] = be[i] * memB[i] + synB[i] - rstB * th[i];
            const bool spA = (memA[i] - th[i]) > 0.0f;
            const bool spB = (memB[i] - th[i]) > 0.0f;

            const unsigned long long a64 = __ballot(spA);
            const unsigned long long b64 = __ballot(spB);
            const unsigned mA = half ? (unsigned)(a64 >> 32) : (unsigned)a64;
            const unsigned mB = half ? (unsigned)(b64 >> 32) : (unsigned)b64;

            float vA[8], vB[8];
#pragma unroll
            for (int g = 0; g < 8; ++g) {
                vA[g] = lut[i][g][(mA >> (4 * g)) & 15u][l];
                vB[g] = lut[i][g][(mB >> (4 * g)) & 15u][l];
            }
            const float accA = ((vA[0] + vA[1]) + (vA[2] + vA[3]))
                             + ((vA[4] + vA[5]) + (vA[6] + vA[7]));
            const float accB = ((vB[0] + vB[1]) + (vB[2] + vB[3]))
                             + ((vB[4] + vB[5]) + (vB[6] + vB[7]));
            if (i < 3) { hA = accA; hB = accB; }
            else       { trA = accA; trB = accB; }
        }

        opA[t * kNF] = trA;
        opB[t * kNF] = trB;

        xvA = xnA;
        xvB = xnB;
    }
}

// ---------------- Kernel 2: feed-forward MLP, in-place on out -------------
__global__ __launch_bounds__(512, 2)
void snn_mlp(const float* __restrict__ W1,
             const float* __restrict__ b1,
             const float* __restrict__ prelu_a,
             const float* __restrict__ W2,
             const float* __restrict__ b2,
             float* out)
{
    const int tid  = threadIdx.x;
    const int lane = tid & 63;
    const int half = lane >> 5;
    const int l    = lane & 31;
    const int l16  = lane & 15;
    const int gbase= l & 16;
    const int gwave= (blockIdx.x * 512 + tid) >> 6;   // 0..16383

    const float pa = prelu_a[0];

    // DPP row_ror direction probe
    const int pr = __builtin_amdgcn_update_dpp(0, lane, 0x121, 0xF, 0xF, true);
    const int d  = (__builtin_amdgcn_readfirstlane(pr) == 1) ? 1 : 15;

    const int lx = l ^ 16;
    unsigned u1_oa[8], u1_ob[8], u1_xa[8], u1_xb[8];
    unsigned u2_o0[8], u2_o1[8], u2_x0[8], u2_x1[8];
#pragma unroll
    for (int q = 0; q < 8; ++q) {
        const int s0 = 2 * q, s1 = 2 * q + 1;
        const int i0 = ((l16 + d * s0) & 15) | gbase;
        const int i1 = ((l16 + d * s1) & 15) | gbase;
        u1_oa[q] = pack_bf16(W1[l         * kF + i0], W1[l         * kF + i1]);
        u1_ob[q] = pack_bf16(W1[(l + 32)  * kF + i0], W1[(l + 32)  * kF + i1]);
        u1_xa[q] = pack_bf16(W1[lx        * kF + i0], W1[lx        * kF + i1]);
        u1_xb[q] = pack_bf16(W1[(lx + 32) * kF + i0], W1[(lx + 32) * kF + i1]);
        u2_o0[q] = pack_bf16(W2[l  * 64 + i0],      W2[l  * 64 + i1]);
        u2_o1[q] = pack_bf16(W2[l  * 64 + i0 + 32], W2[l  * 64 + i1 + 32]);
        u2_x0[q] = pack_bf16(W2[lx * 64 + i0],      W2[lx * 64 + i1]);
        u2_x1[q] = pack_bf16(W2[lx * 64 + i0 + 32], W2[lx * 64 + i1 + 32]);
    }
    const float b1a = b1[l];
    const float b1b = b1[l + 32];
    const float ob  = b2[l];

    // grid-stride: wave handles rows {base..base+3} (A=base+half, B=A+2);
    // 16384 waves * 4 rows * 6 passes = 393216, exact cover.
    for (int base = gwave * 4; base < kRowsTot; base += 16384 * 4) {
        const int rA = base + half;
        const int rB = rA + 2;
        float* pA = out + rA * kF + l;
        float* pB = out + rB * kF + l;
        const float trA = *pA;
        const float trB = *pB;

        float oaA = b1a, obA = b1b, xaA = 0.0f, xbA = 0.0f;
        float oaB = b1a, obB = b1b, xaB = 0.0f, xbB = 0.0f;
        mlp1_steps2<0>(trA, trB, u1_oa, u1_ob, u1_xa, u1_xb,
                       oaA, obA, xaA, xbA, oaB, obB, xaB, xbB);
        const float h1aA = oaA + swz_x16(xaA);
        const float h1bA = obA + swz_x16(xbA);
        const float h1aB = oaB + swz_x16(xaB);
        const float h1bB = obB + swz_x16(xbB);
        const float g1A = (h1aA > 0.0f) ? h1aA : pa * h1aA;
        const float g2A = (h1bA > 0.0f) ? h1bA : pa * h1bA;
        const float g1B = (h1aB > 0.0f) ? h1aB : pa * h1aB;
        const float g2B = (h1bB > 0.0f) ? h1bB : pa * h1bB;

        float ooA = ob, xxA = 0.0f;
        float ooB = ob, xxB = 0.0f;
        mlp2_steps2<0>(g1A, g2A, g1B, g2B, u2_o0, u2_o1, u2_x0, u2_x1,
                       ooA, xxA, ooB, xxB);
        *pA = ooA + swz_x16(xxA);
        *pB = ooB + swz_x16(xxB);
    }
}
} // namespace

extern "C" void kernel_launch(void* const* d_in, const int* in_sizes, int n_in,
                              void* d_out, int out_size, void* d_ws, size_t ws_size,
                              hipStream_t stream) {
    const float* x        = (const float*)d_in[0];
    const float* alphas   = (const float*)d_in[1];
    const float* betas    = (const float*)d_in[2];
    const float* thrs     = (const float*)d_in[3];
    const float* chain_W  = (const float*)d_in[4];
    const float* chain_b  = (const float*)d_in[5];
    const float* lin_W    = (const float*)d_in[6];
    const float* lin_b    = (const float*)d_in[7];
    const float* W1       = (const float*)d_in[8];
    const float* b1       = (const float*)d_in[9];
    const float* prelu_a  = (const float*)d_in[10];
    const float* W2       = (const float*)d_in[11];
    const float* b2       = (const float*)d_in[12];
    float* out            = (float*)d_out;

    // K1: 16384 (b,n) rows / (8 waves * 4 rows) = 512 blocks
    hipLaunchKernelGGL(snn_chain, dim3(512), dim3(512), 0, stream,
                       x, alphas, betas, thrs, chain_W, chain_b, lin_W, lin_b, out);
    // K2: 393216 rows, 2048 blocks * 8 waves * 4 rows * 6 passes (exact)
    hipLaunchKernelGGL(snn_mlp, dim3(2048), dim3(512), 0, stream,
                       W1, b1, prelu_a, W2, b2, out);
}

// Round 15
// 80.694 us; speedup vs baseline: 2.1631x; 1.9895x over previous
//
#include <hip/hip_runtime.h>
#include <hip/hip_bf16.h>

// SNN "SynapticChain": B=4, T=24, N=4096, F=32, L=3 (+1 final synaptic layer).
// R13 resubmit x2 (container unresponsive twice, never benched).
// Keep R12's snn_chain (~41us). Replace DPP-systolic snn_mlp (119us, 4x VALU
// overhead) with MFMA version:
//   - per 16-row tile: layer1 = 4x mfma_f32_16x16x32_bf16 (x2 for hi/lo),
//     prelu, LDS re-fragmentation ([16][68] pad, b128 reads), layer2 = 8 MFMA.
//   - activations hi/lo bf16-split => ~f32 precision; only weights bf16
//     (identical error profile to R12's proven absmax 0.001953125).
//   - k-permutation inside fragments is irrelevant when A and B use the SAME
//     per-lane k order (sum over k is permutation-invariant); relies only on
//     verified C/D layout (col=lane&15, row=(lane>>4)*4+reg) + row/col=lane%16.
//   - biases folded into MFMA C-init. Weights in 32 VGPRs. (512,2) envelope.

namespace {
constexpr int kB = 4;
constexpr int kT = 24;
constexpr int kN = 4096;
constexpr int kF = 32;
constexpr int kNF = kN * kF;

typedef __attribute__((ext_vector_type(8))) short short8v;
typedef __attribute__((ext_vector_type(4))) float float4v;

__device__ __forceinline__ short bfc(float f) {
    return (short)__bfloat16_as_ushort(__float2bfloat16(f));
}
__device__ __forceinline__ float bfc_back(short s) {
    return __bfloat162float(__ushort_as_bfloat16((unsigned short)s));
}

// activations: hi/lo bf16 split (hi + lo reproduces f32 to ~2^-17 rel)
__device__ __forceinline__ void cvt_hilo(const float* v, short8v& hi, short8v& lo) {
#pragma unroll
    for (int e = 0; e < 8; ++e) {
        const short h = bfc(v[e]);
        hi[e] = h;
        lo[e] = bfc(v[e] - bfc_back(h));
    }
}

// weights: plain bf16 (same rounding as R12's proven path)
__device__ __forceinline__ short8v load8w(const float* p) {
    short8v r;
#pragma unroll
    for (int e = 0; e < 8; ++e) r[e] = bfc(p[e]);
    return r;
}

// ---------------- Kernel 1: recurrent chain -> transformed ----------------
__global__ __launch_bounds__(512, 2)
void snn_chain(const float* __restrict__ x,
               const float* __restrict__ alphas,
               const float* __restrict__ betas,
               const float* __restrict__ thrs,
               const float* __restrict__ chain_W,
               const float* __restrict__ chain_b,
               const float* __restrict__ lin_W,
               const float* __restrict__ lin_b,
               float* __restrict__ out)
{
    const int tid  = threadIdx.x;
    const int lane = tid & 63;
    const int half = lane >> 5;
    const int l    = lane & 31;
    const int wid  = tid >> 6;              // 0..7
    const int rowA = blockIdx.x * 32 + wid * 4 + half;
    const int rowB = rowA + 2;
    const int bA   = rowA >> 12;
    const int nA   = rowA & (kN - 1);
    const int bB   = rowB >> 12;
    const int nB   = rowB & (kN - 1);

    __shared__ float lut[4][8][16][32];     // 64 KB

#pragma unroll
    for (int c = 0; c < 2; ++c) {
        const int idx = tid + c * 512;
        const int mat = idx >> 8;
        const int g   = (idx >> 5) & 7;
        const int jj  = idx & 31;
        const float* wsrc = (mat < 3) ? (chain_W + ((mat * kF + jj) * kF + g * 4))
                                      : (lin_W + (jj * kF + g * 4));
        const float4 w = *reinterpret_cast<const float4*>(wsrc);
        const float bias = (g == 0) ? ((mat < 3) ? chain_b[mat * kF + jj] : lin_b[jj])
                                    : 0.0f;
        float s[16];
        s[0]  = 0.0f;
        s[1]  = w.x;         s[2]  = w.y;         s[3]  = w.x + w.y;
        s[4]  = w.z;         s[5]  = w.x + w.z;   s[6]  = w.y + w.z;
        s[7]  = s[3] + w.z;  s[8]  = w.w;         s[9]  = w.x + w.w;
        s[10] = w.y + w.w;   s[11] = s[3] + w.w;  s[12] = w.z + w.w;
        s[13] = s[5] + w.w;  s[14] = s[6] + w.w;  s[15] = s[7] + w.w;
#pragma unroll
        for (int nb = 0; nb < 16; ++nb) lut[mat][g][nb][jj] = s[nb] + bias;
    }
    __syncthreads();

    float al[4], be[4], th[4];
#pragma unroll
    for (int i = 0; i < 4; ++i) {
        al[i] = fminf(fmaxf(alphas[i], 0.0f), 1.0f);
        be[i] = fminf(fmaxf(betas[i],  0.0f), 1.0f);
        th[i] = thrs[i];
    }

    float synA[4] = {0.f, 0.f, 0.f, 0.f};
    float memA[4] = {0.f, 0.f, 0.f, 0.f};
    float synB[4] = {0.f, 0.f, 0.f, 0.f};
    float memB[4] = {0.f, 0.f, 0.f, 0.f};

    const float* xpA = x   + (bA * kT * kN + nA) * kF + l;
    float*       opA = out + (bA * kT * kN + nA) * kF + l;
    const float* xpB = x   + (bB * kT * kN + nB) * kF + l;
    float*       opB = out + (bB * kT * kN + nB) * kF + l;

    float xvA = xpA[0];
    float xvB = xpB[0];

    for (int t = 0; t < kT; ++t) {
        float xnA = 0.0f, xnB = 0.0f;
        if (t + 1 < kT) { xnA = xpA[(t + 1) * kNF]; xnB = xpB[(t + 1) * kNF]; }

        float hA = xvA, hB = xvB;
        float trA = 0.0f, trB = 0.0f;

#pragma unroll
        for (int i = 0; i < 4; ++i) {
            const float rstA = ((memA[i] - th[i]) > 0.0f) ? 1.0f : 0.0f;
            const float rstB = ((memB[i] - th[i]) > 0.0f) ? 1.0f : 0.0f;
            synA[i] = al[i] * synA[i] + hA;
            synB[i] = al[i] * synB[i] + hB;
            memA[i] = be[i] * memA[i] + synA[i] - rstA * th[i];
            memB[i] = be[i] * memB[i] + synB[i] - rstB * th[i];
            const bool spA = (memA[i] - th[i]) > 0.0f;
            const bool spB = (memB[i] - th[i]) > 0.0f;

            const unsigned long long a64 = __ballot(spA);
            const unsigned long long b64 = __ballot(spB);
            const unsigned mA = half ? (unsigned)(a64 >> 32) : (unsigned)a64;
            const unsigned mB = half ? (unsigned)(b64 >> 32) : (unsigned)b64;

            float vA[8], vB[8];
#pragma unroll
            for (int g = 0; g < 8; ++g) {
                vA[g] = lut[i][g][(mA >> (4 * g)) & 15u][l];
                vB[g] = lut[i][g][(mB >> (4 * g)) & 15u][l];
            }
            const float accA = ((vA[0] + vA[1]) + (vA[2] + vA[3]))
                             + ((vA[4] + vA[5]) + (vA[6] + vA[7]));
            const float accB = ((vB[0] + vB[1]) + (vB[2] + vB[3]))
                             + ((vB[4] + vB[5]) + (vB[6] + vB[7]));
            if (i < 3) { hA = accA; hB = accB; }
            else       { trA = accA; trB = accB; }
        }

        opA[t * kNF] = trA;
        opB[t * kNF] = trB;

        xvA = xnA;
        xvB = xnB;
    }
}

// ---------------- Kernel 2: MFMA MLP, in-place on out ---------------------
__global__ __launch_bounds__(512, 2)
void snn_mlp(const float* __restrict__ W1,
             const float* __restrict__ b1,
             const float* __restrict__ prelu_a,
             const float* __restrict__ W2,
             const float* __restrict__ b2,
             float* out)
{
    const int tid   = threadIdx.x;
    const int lane  = tid & 63;
    const int wid   = tid >> 6;             // wave in block, 0..7
    const int l16   = lane & 15;
    const int lg    = lane >> 4;            // 0..3
    const int gwave = (blockIdx.x * 512 + tid) >> 6;   // 0..8191

    // per-wave re-fragmentation buffer; pad 68 -> 2-way banks, 16B-aligned rows
    __shared__ float gbuf[8][16][68];       // 34.8 KB

    const float pa = prelu_a[0];

    // B-fragments (weights), bf16. B[k][c] = W[c][k]; lane: col=l16, k=lg*8+e.
    short8v w1f[4], w2f[2][2];
#pragma unroll
    for (int c0 = 0; c0 < 4; ++c0)
        w1f[c0] = load8w(W1 + (c0 * 16 + l16) * 32 + lg * 8);
#pragma unroll
    for (int c2 = 0; c2 < 2; ++c2)
#pragma unroll
        for (int kb = 0; kb < 2; ++kb)
            w2f[c2][kb] = load8w(W2 + (c2 * 16 + l16) * 64 + kb * 32 + lg * 8);

    float b1v[4], b2v[2];
#pragma unroll
    for (int c0 = 0; c0 < 4; ++c0) b1v[c0] = b1[c0 * 16 + l16];
#pragma unroll
    for (int c2 = 0; c2 < 2; ++c2) b2v[c2] = b2[c2 * 16 + l16];

    // 8192 waves * 3 tiles * 16 rows = 393216 rows, exact cover
    for (int i = 0; i < 3; ++i) {
        const int tile = gwave * 3 + i;
        const int r0   = tile * 16;

        // ---- A1 (activations): row=r0+l16, k=lg*8..+7; hi/lo split
        const float* pin = out + (size_t)(r0 + l16) * kF + lg * 8;
        float tv[8];
        *reinterpret_cast<float4*>(tv)     = *reinterpret_cast<const float4*>(pin);
        *reinterpret_cast<float4*>(tv + 4) = *reinterpret_cast<const float4*>(pin + 4);
        short8v ahi, alo;
        cvt_hilo(tv, ahi, alo);

        // ---- layer 1: H = T @ W1^T + b1 (bias in C-init)
        float4v acc[4];
#pragma unroll
        for (int c0 = 0; c0 < 4; ++c0) {
            float4v c = {b1v[c0], b1v[c0], b1v[c0], b1v[c0]};
            c = __builtin_amdgcn_mfma_f32_16x16x32_bf16(ahi, w1f[c0], c, 0, 0, 0);
            c = __builtin_amdgcn_mfma_f32_16x16x32_bf16(alo, w1f[c0], c, 0, 0, 0);
            acc[c0] = c;
        }

        // ---- prelu + stage to LDS (D layout: row=lg*4+r, col=c0*16+l16)
#pragma unroll
        for (int c0 = 0; c0 < 4; ++c0) {
#pragma unroll
            for (int r = 0; r < 4; ++r) {
                float v = acc[c0][r];
                v = (v > 0.0f) ? v : pa * v;
                gbuf[wid][lg * 4 + r][c0 * 16 + l16] = v;
            }
        }

        // ---- layer 2: O = G @ W2^T + b2; A2 from LDS, hi/lo split
        float4v o[2];
#pragma unroll
        for (int c2 = 0; c2 < 2; ++c2)
            o[c2] = float4v{b2v[c2], b2v[c2], b2v[c2], b2v[c2]};
#pragma unroll
        for (int kb = 0; kb < 2; ++kb) {
            float gv[8];
            const float* pg = &gbuf[wid][l16][kb * 32 + lg * 8];
            *reinterpret_cast<float4*>(gv)     = *reinterpret_cast<const float4*>(pg);
            *reinterpret_cast<float4*>(gv + 4) = *reinterpret_cast<const float4*>(pg + 4);
            short8v ghi, glo;
            cvt_hilo(gv, ghi, glo);
#pragma unroll
            for (int c2 = 0; c2 < 2; ++c2) {
                o[c2] = __builtin_amdgcn_mfma_f32_16x16x32_bf16(ghi, w2f[c2][kb], o[c2], 0, 0, 0);
                o[c2] = __builtin_amdgcn_mfma_f32_16x16x32_bf16(glo, w2f[c2][kb], o[c2], 0, 0, 0);
            }
        }

        // ---- store (D layout)
#pragma unroll
        for (int c2 = 0; c2 < 2; ++c2)
#pragma unroll
            for (int r = 0; r < 4; ++r)
                out[(size_t)(r0 + lg * 4 + r) * kF + c2 * 16 + l16] = o[c2][r];
    }
}
} // namespace

extern "C" void kernel_launch(void* const* d_in, const int* in_sizes, int n_in,
                              void* d_out, int out_size, void* d_ws, size_t ws_size,
                              hipStream_t stream) {
    const float* x        = (const float*)d_in[0];
    const float* alphas   = (const float*)d_in[1];
    const float* betas    = (const float*)d_in[2];
    const float* thrs     = (const float*)d_in[3];
    const float* chain_W  = (const float*)d_in[4];
    const float* chain_b  = (const float*)d_in[5];
    const float* lin_W    = (const float*)d_in[6];
    const float* lin_b    = (const float*)d_in[7];
    const float* W1       = (const float*)d_in[8];
    const float* b1       = (const float*)d_in[9];
    const float* prelu_a  = (const float*)d_in[10];
    const float* W2       = (const float*)d_in[11];
    const float* b2       = (const float*)d_in[12];
    float* out            = (float*)d_out;

    // K1: 16384 (b,n) rows / (8 waves * 4 rows) = 512 blocks
    hipLaunchKernelGGL(snn_chain, dim3(512), dim3(512), 0, stream,
                       x, alphas, betas, thrs, chain_W, chain_b, lin_W, lin_b, out);
    // K2: 24576 tiles of 16 rows; 1024 blocks * 8 waves * 3 tiles (exact)
    hipLaunchKernelGGL(snn_mlp, dim3(1024), dim3(512), 0, stream,
                       W1, b1, prelu_a, W2, b2, out);
}

// Round 17
// 74.040 us; speedup vs baseline: 2.3575x; 1.0899x over previous
//
#include <hip/hip_runtime.h>
#include <hip/hip_bf16.h>

// SNN "SynapticChain": B=4, T=24, N=4096, F=32, L=3 (+1 final synaptic layer).
// R17: R16's MFMA-chain FLIPPED A SPIKE (absmax 0.44 = one-flip cascade) ->
// LAW: recurrent-h arithmetic must stay byte-identical to the proven LUT path.
// Legal cut instead: the lin_out matmul (mat 3, 8 of 32 LDS reads/row-t) does
// NOT feed the recurrence -> move it to the MFMA mlp kernel:
//   snn_chain: LUT mats 0-2 only (48KB), all 4 state updates + ballots
//     byte-identical (bit-identical spikes). Stores layer-3 spike MASK as u32
//     in word 0 of each output row (no transformed store: 50MB -> 1.5MB).
//   snn_mlp: rebuilds exact {0,1} bf16 spikes from mask, transformed =
//     spk@lin_W^T+lin_b via MFMA (double-split bf16 weights, err ~2e-5,
//     non-recurrent = output-tolerance class), D->A bounce via gbuf
//     (R15-verified), then the unchanged proven layer1/2.
// In-place safe: each mlp wave reads its tile's masks before overwriting.

namespace {
constexpr int kB = 4;
constexpr int kT = 24;
constexpr int kN = 4096;
constexpr int kF = 32;
constexpr int kNF = kN * kF;

typedef __attribute__((ext_vector_type(8))) short short8v;
typedef __attribute__((ext_vector_type(4))) float float4v;

__device__ __forceinline__ short bfc(float f) {
    return (short)__bfloat16_as_ushort(__float2bfloat16(f));
}
__device__ __forceinline__ float bfc_back(short s) {
    return __bfloat162float(__ushort_as_bfloat16((unsigned short)s));
}

// activations: hi/lo bf16 split (proven R15)
__device__ __forceinline__ void cvt_hilo(const float* v, short8v& hi, short8v& lo) {
#pragma unroll
    for (int e = 0; e < 8; ++e) {
        const short h = bfc(v[e]);
        hi[e] = h;
        lo[e] = bfc(v[e] - bfc_back(h));
    }
}

__device__ __forceinline__ short8v load8w(const float* p) {
    short8v r;
#pragma unroll
    for (int e = 0; e < 8; ++e) r[e] = bfc(p[e]);
    return r;
}

// ---------------- Kernel 1: recurrent chain -> spike masks ----------------
__global__ __launch_bounds__(512, 2)
void snn_chain(const float* __restrict__ x,
               const float* __restrict__ alphas,
               const float* __restrict__ betas,
               const float* __restrict__ thrs,
               const float* __restrict__ chain_W,
               const float* __restrict__ chain_b,
               float* __restrict__ out)
{
    const int tid  = threadIdx.x;
    const int lane = tid & 63;
    const int half = lane >> 5;
    const int l    = lane & 31;
    const int wid  = tid >> 6;              // 0..7
    const int rowA = blockIdx.x * 32 + wid * 4 + half;
    const int rowB = rowA + 2;
    const int bA   = rowA >> 12;
    const int nA   = rowA & (kN - 1);
    const int bB   = rowB >> 12;
    const int nB   = rowB & (kN - 1);

    __shared__ float lut[3][8][16][32];     // 48 KB (mats 0..2 only)

    // LUT init: 768 (mat,g,j) combos; arithmetic identical to R12/R15
#pragma unroll
    for (int c = 0; c < 2; ++c) {
        const int idx = tid + c * 512;
        if (idx < 768) {
            const int mat = idx >> 8;           // 0..2
            const int g   = (idx >> 5) & 7;
            const int jj  = idx & 31;
            const float* wsrc = chain_W + ((mat * kF + jj) * kF + g * 4);
            const float4 w = *reinterpret_cast<const float4*>(wsrc);
            const float bias = (g == 0) ? chain_b[mat * kF + jj] : 0.0f;
            float s[16];
            s[0]  = 0.0f;
            s[1]  = w.x;         s[2]  = w.y;         s[3]  = w.x + w.y;
            s[4]  = w.z;         s[5]  = w.x + w.z;   s[6]  = w.y + w.z;
            s[7]  = s[3] + w.z;  s[8]  = w.w;         s[9]  = w.x + w.w;
            s[10] = w.y + w.w;   s[11] = s[3] + w.w;  s[12] = w.z + w.w;
            s[13] = s[5] + w.w;  s[14] = s[6] + w.w;  s[15] = s[7] + w.w;
#pragma unroll
            for (int nb = 0; nb < 16; ++nb) lut[mat][g][nb][jj] = s[nb] + bias;
        }
    }
    __syncthreads();

    float al[4], be[4], th[4];
#pragma unroll
    for (int i = 0; i < 4; ++i) {
        al[i] = fminf(fmaxf(alphas[i], 0.0f), 1.0f);
        be[i] = fminf(fmaxf(betas[i],  0.0f), 1.0f);
        th[i] = thrs[i];
    }

    float synA[4] = {0.f, 0.f, 0.f, 0.f};
    float memA[4] = {0.f, 0.f, 0.f, 0.f};
    float synB[4] = {0.f, 0.f, 0.f, 0.f};
    float memB[4] = {0.f, 0.f, 0.f, 0.f};

    const float* xpA = x   + (size_t)(bA * kT * kN + nA) * kF + l;
    float*       opA = out + (size_t)(bA * kT * kN + nA) * kF + l;
    const float* xpB = x   + (size_t)(bB * kT * kN + nB) * kF + l;
    float*       opB = out + (size_t)(bB * kT * kN + nB) * kF + l;

    float xvA = xpA[0];
    float xvB = xpB[0];

    for (int t = 0; t < kT; ++t) {
        float xnA = 0.0f, xnB = 0.0f;
        if (t + 1 < kT) { xnA = xpA[(size_t)(t + 1) * kNF]; xnB = xpB[(size_t)(t + 1) * kNF]; }

        float hA = xvA, hB = xvB;

#pragma unroll
        for (int i = 0; i < 4; ++i) {
            // state update: byte-identical to R12/R15 (bit-identical spikes)
            const float rstA = ((memA[i] - th[i]) > 0.0f) ? 1.0f : 0.0f;
            const float rstB = ((memB[i] - th[i]) > 0.0f) ? 1.0f : 0.0f;
            synA[i] = al[i] * synA[i] + hA;
            synB[i] = al[i] * synB[i] + hB;
            memA[i] = be[i] * memA[i] + synA[i] - rstA * th[i];
            memB[i] = be[i] * memB[i] + synB[i] - rstB * th[i];
            const bool spA = (memA[i] - th[i]) > 0.0f;
            const bool spB = (memB[i] - th[i]) > 0.0f;

            const unsigned long long a64 = __ballot(spA);
            const unsigned long long b64 = __ballot(spB);
            const unsigned mA = half ? (unsigned)(a64 >> 32) : (unsigned)a64;
            const unsigned mB = half ? (unsigned)(b64 >> 32) : (unsigned)b64;

            if (i < 3) {
                // binary matmul via nibble LUT: arithmetic identical
                float vA[8], vB[8];
#pragma unroll
                for (int g = 0; g < 8; ++g) {
                    vA[g] = lut[i][g][(mA >> (4 * g)) & 15u][l];
                    vB[g] = lut[i][g][(mB >> (4 * g)) & 15u][l];
                }
                hA = ((vA[0] + vA[1]) + (vA[2] + vA[3]))
                   + ((vA[4] + vA[5]) + (vA[6] + vA[7]));
                hB = ((vB[0] + vB[1]) + (vB[2] + vB[3]))
                   + ((vB[4] + vB[5]) + (vB[6] + vB[7]));
            } else if (l == 0) {
                // store layer-3 spike mask into word 0 of the output row
                *reinterpret_cast<unsigned*>(opA + (size_t)t * kNF) = mA;
                *reinterpret_cast<unsigned*>(opB + (size_t)t * kNF) = mB;
            }
        }

        xvA = xnA;
        xvB = xnB;
    }
}

// ------- Kernel 2: MFMA lin_out + MLP from spike masks, in-place ----------
__global__ __launch_bounds__(512, 2)
void snn_mlp(const float* __restrict__ lin_W,
             const float* __restrict__ lin_b,
             const float* __restrict__ W1,
             const float* __restrict__ b1,
             const float* __restrict__ prelu_a,
             const float* __restrict__ W2,
             const float* __restrict__ b2,
             float* out)
{
    const int tid   = threadIdx.x;
    const int lane  = tid & 63;
    const int wid   = tid >> 6;             // wave in block, 0..7
    const int l16   = lane & 15;
    const int lg    = lane >> 4;            // 0..3
    const int gwave = (blockIdx.x * 512 + tid) >> 6;   // 0..8191

    __shared__ float gbuf[8][16][68];       // 34.8 KB

    const float pa = prelu_a[0];

    // lin_out B-fragments: double-split bf16 (spikes exact {0,1}; err ~2e-5)
    short8v lf[2][2];                       // [col][split]
#pragma unroll
    for (int c = 0; c < 2; ++c) {
#pragma unroll
        for (int e = 0; e < 8; ++e) {
            const float w  = lin_W[(c * 16 + l16) * 32 + lg * 8 + e];
            const short s0 = bfc(w);
            const short s1 = bfc(w - bfc_back(s0));
            lf[c][0][e] = s0;
            lf[c][1][e] = s1;
        }
    }
    float lbv[2];
#pragma unroll
    for (int c = 0; c < 2; ++c) lbv[c] = lin_b[c * 16 + l16];

    short8v w1f[4], w2f[2][2];
#pragma unroll
    for (int c0 = 0; c0 < 4; ++c0)
        w1f[c0] = load8w(W1 + (c0 * 16 + l16) * 32 + lg * 8);
#pragma unroll
    for (int c2 = 0; c2 < 2; ++c2)
#pragma unroll
        for (int kb = 0; kb < 2; ++kb)
            w2f[c2][kb] = load8w(W2 + (c2 * 16 + l16) * 64 + kb * 32 + lg * 8);

    float b1v[4], b2v[2];
#pragma unroll
    for (int c0 = 0; c0 < 4; ++c0) b1v[c0] = b1[c0 * 16 + l16];
#pragma unroll
    for (int c2 = 0; c2 < 2; ++c2) b2v[c2] = b2[c2 * 16 + l16];

    for (int i = 0; i < 3; ++i) {
        const int tile = gwave * 3 + i;
        const int r0   = tile * 16;

        // ---- read the row's spike mask; rebuild exact {0,1} bf16 A-frag
        const unsigned m =
            *reinterpret_cast<const unsigned*>(out + (size_t)(r0 + l16) * kF);
        short8v aspk;
#pragma unroll
        for (int e = 0; e < 8; ++e)
            aspk[e] = ((m >> (lg * 8 + e)) & 1u) ? (short)0x3F80 : (short)0;

        // ---- lin_out: transformed = spk @ lin_W^T + lin_b
        float4v t0 = {lbv[0], lbv[0], lbv[0], lbv[0]};
        float4v t1 = {lbv[1], lbv[1], lbv[1], lbv[1]};
        t0 = __builtin_amdgcn_mfma_f32_16x16x32_bf16(aspk, lf[0][0], t0, 0, 0, 0);
        t0 = __builtin_amdgcn_mfma_f32_16x16x32_bf16(aspk, lf[0][1], t0, 0, 0, 0);
        t1 = __builtin_amdgcn_mfma_f32_16x16x32_bf16(aspk, lf[1][0], t1, 0, 0, 0);
        t1 = __builtin_amdgcn_mfma_f32_16x16x32_bf16(aspk, lf[1][1], t1, 0, 0, 0);

        // ---- D -> A-layout bounce via per-wave gbuf (R15-verified pattern)
#pragma unroll
        for (int r = 0; r < 4; ++r) {
            gbuf[wid][lg * 4 + r][l16]      = t0[r];
            gbuf[wid][lg * 4 + r][16 + l16] = t1[r];
        }
        float tv[8];
        const float* pt = &gbuf[wid][l16][lg * 8];
        *reinterpret_cast<float4*>(tv)     = *reinterpret_cast<const float4*>(pt);
        *reinterpret_cast<float4*>(tv + 4) = *reinterpret_cast<const float4*>(pt + 4);
        short8v ahi, alo;
        cvt_hilo(tv, ahi, alo);

        // ---- layer 1: H = T @ W1^T + b1 (proven R15)
        float4v acc[4];
#pragma unroll
        for (int c0 = 0; c0 < 4; ++c0) {
            float4v c = {b1v[c0], b1v[c0], b1v[c0], b1v[c0]};
            c = __builtin_amdgcn_mfma_f32_16x16x32_bf16(ahi, w1f[c0], c, 0, 0, 0);
            c = __builtin_amdgcn_mfma_f32_16x16x32_bf16(alo, w1f[c0], c, 0, 0, 0);
            acc[c0] = c;
        }

#pragma unroll
        for (int c0 = 0; c0 < 4; ++c0) {
#pragma unroll
            for (int r = 0; r < 4; ++r) {
                float v = acc[c0][r];
                v = (v > 0.0f) ? v : pa * v;
                gbuf[wid][lg * 4 + r][c0 * 16 + l16] = v;
            }
        }

        // ---- layer 2: O = G @ W2^T + b2 (proven R15)
        float4v o[2];
#pragma unroll
        for (int c2 = 0; c2 < 2; ++c2)
            o[c2] = float4v{b2v[c2], b2v[c2], b2v[c2], b2v[c2]};
#pragma unroll
        for (int kb = 0; kb < 2; ++kb) {
            float gv[8];
            const float* pg = &gbuf[wid][l16][kb * 32 + lg * 8];
            *reinterpret_cast<float4*>(gv)     = *reinterpret_cast<const float4*>(pg);
            *reinterpret_cast<float4*>(gv + 4) = *reinterpret_cast<const float4*>(pg + 4);
            short8v ghi, glo;
            cvt_hilo(gv, ghi, glo);
#pragma unroll
            for (int c2 = 0; c2 < 2; ++c2) {
                o[c2] = __builtin_amdgcn_mfma_f32_16x16x32_bf16(ghi, w2f[c2][kb], o[c2], 0, 0, 0);
                o[c2] = __builtin_amdgcn_mfma_f32_16x16x32_bf16(glo, w2f[c2][kb], o[c2], 0, 0, 0);
            }
        }

#pragma unroll
        for (int c2 = 0; c2 < 2; ++c2)
#pragma unroll
            for (int r = 0; r < 4; ++r)
                out[(size_t)(r0 + lg * 4 + r) * kF + c2 * 16 + l16] = o[c2][r];
    }
}
} // namespace

extern "C" void kernel_launch(void* const* d_in, const int* in_sizes, int n_in,
                              void* d_out, int out_size, void* d_ws, size_t ws_size,
                              hipStream_t stream) {
    const float* x        = (const float*)d_in[0];
    const float* alphas   = (const float*)d_in[1];
    const float* betas    = (const float*)d_in[2];
    const float* thrs     = (const float*)d_in[3];
    const float* chain_W  = (const float*)d_in[4];
    const float* chain_b  = (const float*)d_in[5];
    const float* lin_W    = (const float*)d_in[6];
    const float* lin_b    = (const float*)d_in[7];
    const float* W1       = (const float*)d_in[8];
    const float* b1       = (const float*)d_in[9];
    const float* prelu_a  = (const float*)d_in[10];
    const float* W2       = (const float*)d_in[11];
    const float* b2       = (const float*)d_in[12];
    float* out            = (float*)d_out;

    // K1: 16384 (b,n) rows / (8 waves * 4 rows) = 512 blocks; writes masks
    hipLaunchKernelGGL(snn_chain, dim3(512), dim3(512), 0, stream,
                       x, alphas, betas, thrs, chain_W, chain_b, out);
    // K2: 24576 tiles of 16 rows; 1024 blocks * 8 waves * 3 tiles (exact)
    hipLaunchKernelGGL(snn_mlp, dim3(1024), dim3(512), 0, stream,
                       lin_W, lin_b, W1, b1, prelu_a, W2, b2, out);
}

// Round 18
// 72.582 us; speedup vs baseline: 2.4049x; 1.0201x over previous
//
#include <hip/hip_runtime.h>
#include <hip/hip_bf16.h>

// SNN "SynapticChain": B=4, T=24, N=4096, F=32, L=3 (+1 final synaptic layer).
// R18: FUSE chain+mlp at wave granularity. R17 showed chain is latency-bound
// (LDS ~15us, VALU ~30us of 51.5us, occ 28%) with ~20us of mlp serialized
// behind it on idle pipes. Here each wave runs 4 byte-identical chain steps
// (2 rows/lane, LUT mats 0-2, R12-proven arithmetic -> bit-identical spikes),
// parks the 4 layer-3 masks in a 512B per-wave LDS buffer (exact u32,
// same-wave in-order DS, no barrier), then executes one 16-row MFMA tile
// (4 bn-rows x 4 t): mask->spikes->lin_out (double-split bf16, R17-proven)
// -> gbuf bounce -> layer1/prelu/layer2 (R15-proven, hi/lo activations).
// MFMA/VMEM work of mlp-phase waves fills chain-phase waves' latency bubbles.
// out written exactly once (masks never hit HBM). LDS 67KB -> 2 blocks/CU.
// alpha/beta/thr -> SGPR via readfirstlane (value-identical, -12 VGPR).

namespace {
constexpr int kB = 4;
constexpr int kT = 24;
constexpr int kN = 4096;
constexpr int kF = 32;
constexpr int kNF = kN * kF;

typedef __attribute__((ext_vector_type(8))) short short8v;
typedef __attribute__((ext_vector_type(4))) float float4v;

__device__ __forceinline__ short bfc(float f) {
    return (short)__bfloat16_as_ushort(__float2bfloat16(f));
}
__device__ __forceinline__ float bfc_back(short s) {
    return __bfloat162float(__ushort_as_bfloat16((unsigned short)s));
}
__device__ __forceinline__ float uni(float v) {
    return __int_as_float(__builtin_amdgcn_readfirstlane(__float_as_int(v)));
}

// activations: hi/lo bf16 split (proven R15)
__device__ __forceinline__ void cvt_hilo(const float* v, short8v& hi, short8v& lo) {
#pragma unroll
    for (int e = 0; e < 8; ++e) {
        const short h = bfc(v[e]);
        hi[e] = h;
        lo[e] = bfc(v[e] - bfc_back(h));
    }
}

__device__ __forceinline__ short8v load8w(const float* p) {
    short8v r;
#pragma unroll
    for (int e = 0; e < 8; ++e) r[e] = bfc(p[e]);
    return r;
}

__global__ __launch_bounds__(512, 2)
void snn_fused(const float* __restrict__ x,
               const float* __restrict__ alphas,
               const float* __restrict__ betas,
               const float* __restrict__ thrs,
               const float* __restrict__ chain_W,
               const float* __restrict__ chain_b,
               const float* __restrict__ lin_W,
               const float* __restrict__ lin_b,
               const float* __restrict__ W1,
               const float* __restrict__ b1,
               const float* __restrict__ prelu_a,
               const float* __restrict__ W2,
               const float* __restrict__ b2,
               float* __restrict__ out)
{
    const int tid  = threadIdx.x;
    const int lane = tid & 63;
    const int half = lane >> 5;             // chain: row-half
    const int l    = lane & 31;             // chain: feature
    const int wid  = tid >> 6;              // 0..7
    const int l16  = lane & 15;             // mfma: row/col in 16
    const int lg   = lane >> 4;             // mfma: 0..3

    const int base = blockIdx.x * 32 + wid * 4;   // wave's 4 bn-rows
    const int rowA = base + half;
    const int rowB = rowA + 2;
    const int bA   = rowA >> 12;
    const int nA   = rowA & (kN - 1);
    const int bB   = rowB >> 12;
    const int nB   = rowB & (kN - 1);
    const int bq   = base >> 12;
    const int n0   = base & (kN - 1);

    __shared__ float    lut[3][8][16][32];  // 48 KB (mats 0..2)
    __shared__ float    gbuf[8][16][36];    // 18.4 KB per-wave bounce tiles
    __shared__ unsigned mlds[8][4][4];      // per-wave layer-3 masks [tt][sel]

    // ---- LUT init: byte-identical arithmetic to R12/R17
#pragma unroll
    for (int c = 0; c < 2; ++c) {
        const int idx = tid + c * 512;
        if (idx < 768) {
            const int mat = idx >> 8;
            const int g   = (idx >> 5) & 7;
            const int jj  = idx & 31;
            const float* wsrc = chain_W + ((mat * kF + jj) * kF + g * 4);
            const float4 w = *reinterpret_cast<const float4*>(wsrc);
            const float bias = (g == 0) ? chain_b[mat * kF + jj] : 0.0f;
            float s[16];
            s[0]  = 0.0f;
            s[1]  = w.x;         s[2]  = w.y;         s[3]  = w.x + w.y;
            s[4]  = w.z;         s[5]  = w.x + w.z;   s[6]  = w.y + w.z;
            s[7]  = s[3] + w.z;  s[8]  = w.w;         s[9]  = w.x + w.w;
            s[10] = w.y + w.w;   s[11] = s[3] + w.w;  s[12] = w.z + w.w;
            s[13] = s[5] + w.w;  s[14] = s[6] + w.w;  s[15] = s[7] + w.w;
#pragma unroll
            for (int nb = 0; nb < 16; ++nb) lut[mat][g][nb][jj] = s[nb] + bias;
        }
    }
    __syncthreads();

    // ---- uniform scalars -> SGPR (values identical; saves VGPR)
    float al[4], be[4], th[4];
#pragma unroll
    for (int i = 0; i < 4; ++i) {
        al[i] = uni(fminf(fmaxf(alphas[i], 0.0f), 1.0f));
        be[i] = uni(fminf(fmaxf(betas[i],  0.0f), 1.0f));
        th[i] = uni(thrs[i]);
    }
    const float pa = uni(prelu_a[0]);

    // ---- mlp weight fragments (R17-proven forms)
    short8v lf[2][2];                       // lin_out double-split
#pragma unroll
    for (int c = 0; c < 2; ++c) {
#pragma unroll
        for (int e = 0; e < 8; ++e) {
            const float w  = lin_W[(c * 16 + l16) * 32 + lg * 8 + e];
            const short s0 = bfc(w);
            const short s1 = bfc(w - bfc_back(s0));
            lf[c][0][e] = s0;
            lf[c][1][e] = s1;
        }
    }
    float lbv[2];
#pragma unroll
    for (int c = 0; c < 2; ++c) lbv[c] = lin_b[c * 16 + l16];

    short8v w1f[4], w2f[2][2];
#pragma unroll
    for (int c0 = 0; c0 < 4; ++c0)
        w1f[c0] = load8w(W1 + (c0 * 16 + l16) * 32 + lg * 8);
#pragma unroll
    for (int c2 = 0; c2 < 2; ++c2)
#pragma unroll
        for (int kb = 0; kb < 2; ++kb)
            w2f[c2][kb] = load8w(W2 + (c2 * 16 + l16) * 64 + kb * 32 + lg * 8);

    float b1v[4], b2v[2];
#pragma unroll
    for (int c0 = 0; c0 < 4; ++c0) b1v[c0] = b1[c0 * 16 + l16];
#pragma unroll
    for (int c2 = 0; c2 < 2; ++c2) b2v[c2] = b2[c2 * 16 + l16];

    // ---- chain state
    float synA[4] = {0.f, 0.f, 0.f, 0.f};
    float memA[4] = {0.f, 0.f, 0.f, 0.f};
    float synB[4] = {0.f, 0.f, 0.f, 0.f};
    float memB[4] = {0.f, 0.f, 0.f, 0.f};

    const float* xpA = x + (size_t)(bA * kT * kN + nA) * kF + l;
    const float* xpB = x + (size_t)(bB * kT * kN + nB) * kF + l;

    float xvA = xpA[0];
    float xvB = xpB[0];

    for (int tb = 0; tb < 6; ++tb) {
        // ======== 4 chain steps (byte-identical recurrent arithmetic) ======
        for (int tt = 0; tt < 4; ++tt) {
            const int t = tb * 4 + tt;
            float xnA = 0.0f, xnB = 0.0f;
            if (t + 1 < kT) {
                xnA = xpA[(size_t)(t + 1) * kNF];
                xnB = xpB[(size_t)(t + 1) * kNF];
            }

            float hA = xvA, hB = xvB;

#pragma unroll
            for (int i = 0; i < 4; ++i) {
                const float rstA = ((memA[i] - th[i]) > 0.0f) ? 1.0f : 0.0f;
                const float rstB = ((memB[i] - th[i]) > 0.0f) ? 1.0f : 0.0f;
                synA[i] = al[i] * synA[i] + hA;
                synB[i] = al[i] * synB[i] + hB;
                memA[i] = be[i] * memA[i] + synA[i] - rstA * th[i];
                memB[i] = be[i] * memB[i] + synB[i] - rstB * th[i];
                const bool spA = (memA[i] - th[i]) > 0.0f;
                const bool spB = (memB[i] - th[i]) > 0.0f;

                const unsigned long long a64 = __ballot(spA);
                const unsigned long long b64 = __ballot(spB);
                const unsigned mA = half ? (unsigned)(a64 >> 32) : (unsigned)a64;
                const unsigned mB = half ? (unsigned)(b64 >> 32) : (unsigned)b64;

                if (i < 3) {
                    float vA[8], vB[8];
#pragma unroll
                    for (int g = 0; g < 8; ++g) {
                        vA[g] = lut[i][g][(mA >> (4 * g)) & 15u][l];
                        vB[g] = lut[i][g][(mB >> (4 * g)) & 15u][l];
                    }
                    hA = ((vA[0] + vA[1]) + (vA[2] + vA[3]))
                       + ((vA[4] + vA[5]) + (vA[6] + vA[7]));
                    hB = ((vB[0] + vB[1]) + (vB[2] + vB[3]))
                       + ((vB[4] + vB[5]) + (vB[6] + vB[7]));
                } else if (l == 0) {
                    mlds[wid][tt][half]     = mA;   // bn = base+half
                    mlds[wid][tt][2 + half] = mB;   // bn = base+2+half
                }
            }

            xvA = xnA;
            xvB = xnB;
        }

        // ======== one MFMA tile: 4 bn-rows x 4 t (rows v: bn=base+(v&3),
        // t=tb*4+(v>>2)); same-wave LDS is in-order -> no barrier needed ====
        const unsigned m = mlds[wid][l16 >> 2][l16 & 3];
        short8v aspk;
#pragma unroll
        for (int e = 0; e < 8; ++e)
            aspk[e] = ((m >> (lg * 8 + e)) & 1u) ? (short)0x3F80 : (short)0;

        // lin_out: transformed = spk @ lin_W^T + lin_b
        float4v t0 = {lbv[0], lbv[0], lbv[0], lbv[0]};
        float4v t1 = {lbv[1], lbv[1], lbv[1], lbv[1]};
        t0 = __builtin_amdgcn_mfma_f32_16x16x32_bf16(aspk, lf[0][0], t0, 0, 0, 0);
        t0 = __builtin_amdgcn_mfma_f32_16x16x32_bf16(aspk, lf[0][1], t0, 0, 0, 0);
        t1 = __builtin_amdgcn_mfma_f32_16x16x32_bf16(aspk, lf[1][0], t1, 0, 0, 0);
        t1 = __builtin_amdgcn_mfma_f32_16x16x32_bf16(aspk, lf[1][1], t1, 0, 0, 0);

        // D -> A-layout bounce (T tile 16x32)
#pragma unroll
        for (int r = 0; r < 4; ++r) {
            gbuf[wid][lg * 4 + r][l16]      = t0[r];
            gbuf[wid][lg * 4 + r][16 + l16] = t1[r];
        }
        float tv[8];
        {
            const float* pt = &gbuf[wid][l16][lg * 8];
            *reinterpret_cast<float4*>(tv)     = *reinterpret_cast<const float4*>(pt);
            *reinterpret_cast<float4*>(tv + 4) = *reinterpret_cast<const float4*>(pt + 4);
        }
        short8v ahi, alo;
        cvt_hilo(tv, ahi, alo);

        // layer1 + prelu + layer2, in two 32-col halves (gbuf reused)
        float4v o[2];
#pragma unroll
        for (int c2 = 0; c2 < 2; ++c2)
            o[c2] = float4v{b2v[c2], b2v[c2], b2v[c2], b2v[c2]};

#pragma unroll
        for (int hb = 0; hb < 2; ++hb) {       // hb: c0 pair {0,1} / {2,3}
#pragma unroll
            for (int cc = 0; cc < 2; ++cc) {
                const int c0 = hb * 2 + cc;
                float4v c = {b1v[c0], b1v[c0], b1v[c0], b1v[c0]};
                c = __builtin_amdgcn_mfma_f32_16x16x32_bf16(ahi, w1f[c0], c, 0, 0, 0);
                c = __builtin_amdgcn_mfma_f32_16x16x32_bf16(alo, w1f[c0], c, 0, 0, 0);
                // prelu + stage this 16x16 quadrant into gbuf cols cc*16
#pragma unroll
                for (int r = 0; r < 4; ++r) {
                    float v = c[r];
                    v = (v > 0.0f) ? v : pa * v;
                    gbuf[wid][lg * 4 + r][cc * 16 + l16] = v;
                }
            }
            // consume this 32-col half of G as layer2 k-block hb
            float gv[8];
            const float* pg = &gbuf[wid][l16][lg * 8];
            *reinterpret_cast<float4*>(gv)     = *reinterpret_cast<const float4*>(pg);
            *reinterpret_cast<float4*>(gv + 4) = *reinterpret_cast<const float4*>(pg + 4);
            short8v ghi, glo;
            cvt_hilo(gv, ghi, glo);
#pragma unroll
            for (int c2 = 0; c2 < 2; ++c2) {
                o[c2] = __builtin_amdgcn_mfma_f32_16x16x32_bf16(ghi, w2f[c2][hb], o[c2], 0, 0, 0);
                o[c2] = __builtin_amdgcn_mfma_f32_16x16x32_bf16(glo, w2f[c2][hb], o[c2], 0, 0, 0);
            }
        }

        // stores: D row v=lg*4+r -> bn=base+r, t=tb*4+lg
        float* ob = out + ((size_t)(bq * kT + tb * 4 + lg) * kN + n0) * kF + l16;
#pragma unroll
        for (int c2 = 0; c2 < 2; ++c2)
#pragma unroll
            for (int r = 0; r < 4; ++r)
                ob[(size_t)r * kF + c2 * 16] = o[c2][r];
    }
}
} // namespace

extern "C" void kernel_launch(void* const* d_in, const int* in_sizes, int n_in,
                              void* d_out, int out_size, void* d_ws, size_t ws_size,
                              hipStream_t stream) {
    const float* x        = (const float*)d_in[0];
    const float* alphas   = (const float*)d_in[1];
    const float* betas    = (const float*)d_in[2];
    const float* thrs     = (const float*)d_in[3];
    const float* chain_W  = (const float*)d_in[4];
    const float* chain_b  = (const float*)d_in[5];
    const float* lin_W    = (const float*)d_in[6];
    const float* lin_b    = (const float*)d_in[7];
    const float* W1       = (const float*)d_in[8];
    const float* b1       = (const float*)d_in[9];
    const float* prelu_a  = (const float*)d_in[10];
    const float* W2       = (const float*)d_in[11];
    const float* b2       = (const float*)d_in[12];
    float* out            = (float*)d_out;

    // 512 blocks * 8 waves * 4 bn-rows = 16384 rows; chain+mlp fused
    hipLaunchKernelGGL(snn_fused, dim3(512), dim3(512), 0, stream,
                       x, alphas, betas, thrs, chain_W, chain_b, lin_W, lin_b,
                       W1, b1, prelu_a, W2, b2, out);
}